// Round 1
// baseline (561.319 us; speedup 1.0000x reference)
//
#include <hip/hip_runtime.h>
#include <math.h>

// RealNVP, 8 layers, B=262144 samples, H=128 hidden, scalar coupling input.
// Exact piecewise-linear factorization: h2_pre[b,i] = x_b*S1[k,i] + S0[k,i],
// k = #{j : t_j < x_b}. BN stats computed exactly from per-interval moments.

#define BN_ 262144
#define H_ 128
#define NBINS 129
#define SSTR 132          // global S-table row stride (float2)
#define LSTR 130          // LDS tile row stride (float2)

// ws layout (float offsets)
#define OFF_ST  (3*BN_)          // 4 floats: stats[par]={sum,sumsq}, par=0,1
#define OFF_BIN (3*BN_+8)        // 512 floats: cnt[0..131], sx[132..263], sxx[264..395]
#define OFF_T   (3*BN_+520)      // 128 floats: breakpoints (unsorted)
#define OFF_S   (3*BN_+648)      // float2[128*132]: S-table, row i, col k
#define OFF_BB  (3*BN_+648+2*128*132) // uchar[B]: per-sample bin

__global__ void k_zero(float* ws) {
    if (threadIdx.x < 4) ws[OFF_ST + threadIdx.x] = 0.f;
}

__global__ __launch_bounds__(1024) void k_init(const float* __restrict__ x,
                                               float* __restrict__ ws) {
    int b = blockIdx.x * 1024 + threadIdx.x;
    float2 xv = ((const float2*)x)[b];
    ws[b] = xv.x;              // x0
    ws[BN_ + b] = xv.y;        // x1
    ws[2*BN_ + b] = 0.f;       // sldj
    // layer 0 uses xin = x1: reduce sum, sumsq into stats[0]
    float s = xv.y, ss = xv.y * xv.y;
    for (int off = 32; off; off >>= 1) {
        s += __shfl_down(s, off);
        ss += __shfl_down(ss, off);
    }
    __shared__ float rs[16], rss[16];
    int lane = threadIdx.x & 63, wid = threadIdx.x >> 6;
    if (lane == 0) { rs[wid] = s; rss[wid] = ss; }
    __syncthreads();
    if (threadIdx.x == 0) {
        float a = 0.f, c = 0.f;
        for (int w = 0; w < 16; w++) { a += rs[w]; c += rss[w]; }
        atomicAdd(&ws[OFF_ST + 0], a);
        atomicAdd(&ws[OFF_ST + 1], c);
    }
}

__device__ __forceinline__ float bred128(float v, volatile float* tmp, int tid) {
    for (int off = 32; off; off >>= 1) v += __shfl_down(v, off);
    if ((tid & 63) == 0) tmp[tid >> 6] = v;
    __syncthreads();
    float r = tmp[0] + tmp[1];
    __syncthreads();
    return r;
}

// 128 blocks x 128 threads: block i builds S-table row i (all 129 intervals)
// via a prefix scan over sorted relu-breakpoint toggles. Block 0 also writes
// breakpoints, zeroes bins and next-layer stats slot.
__global__ __launch_bounds__(128) void k_prep(
    const float* __restrict__ v1, const float* __restrict__ g1,
    const float* __restrict__ bn1g, const float* __restrict__ bn1b,
    const float* __restrict__ v2, const float* __restrict__ g2,
    const float* __restrict__ b2,
    float* __restrict__ ws, int l, int par) {
    const int j = threadIdx.x, i = blockIdx.x;
    __shared__ float sA[H_], sC[H_], sT[H_], vrow[H_];
    __shared__ int order[H_];
    __shared__ float2 scan2[H_];
    __shared__ float red[2];

    float Ssum = ws[OFF_ST + 2*par], SSq = ws[OFF_ST + 2*par + 1];
    float mx = Ssum * (1.f / BN_);
    float vx = fmaxf(SSq * (1.f / BN_) - mx * mx, 0.f);

    // BN1 folded: h1_j = relu(a_j*x + c_j); b1 cancels exactly in BN.
    float g1v = g1[l*H_ + j];
    float w1 = (v1[l*H_ + j] >= 0.f) ? g1v : -g1v;      // g1*sign(v1)
    float r = rsqrtf(vx * g1v * g1v + 1e-5f);
    float a = w1 * r * bn1g[l*H_ + j];
    float c = bn1b[l*H_ + j] - mx * a;
    float tj = (a != 0.f) ? (-c / a) : 3.0e38f;
    sA[j] = a; sC[j] = c; sT[j] = tj;
    __syncthreads();

    int rk = 0;
    for (int q = 0; q < H_; q++) {
        float tq = sT[q];
        rk += ((tq < tj) || (tq == tj && q < j)) ? 1 : 0;
    }
    order[rk] = j;                                       // permutation

    float vv = v2[l*H_*H_ + i*H_ + j];
    vrow[j] = vv;
    float n2 = bred128(vv * vv, red, j);                 // also syncs order/vrow
    float wsc = g2[l*H_ + i] / sqrtf(n2);
    float w = wsc * vv;
    bool bm = (a < 0.f) || (a == 0.f && c > 0.f);        // active at x=-inf
    float base1 = bred128(bm ? w * a : 0.f, red, j);
    float base0 = bred128(bm ? w * c : 0.f, red, j);

    // delta for interval step k = j+1: toggle unit order[j]
    int jj = order[j];
    float aa = sA[jj], cc = sC[jj], vj = vrow[jj];
    float d1 = 0.f, d0 = 0.f;
    if (aa != 0.f) {
        float sg = (aa > 0.f) ? 1.f : -1.f;
        float wj = wsc * vj;
        d1 = sg * wj * aa; d0 = sg * wj * cc;
    }
    scan2[j] = make_float2(d1, d0);
    __syncthreads();
    for (int off = 1; off < H_; off <<= 1) {
        float2 add = (j >= off) ? scan2[j - off] : make_float2(0.f, 0.f);
        __syncthreads();
        scan2[j].x += add.x; scan2[j].y += add.y;
        __syncthreads();
    }
    float b2i = b2[l*H_ + i];
    float2* Srow = (float2*)(ws + OFF_S) + i * SSTR;
    float2 sj = scan2[j];
    Srow[j + 1] = make_float2(base1 + sj.x, base0 + sj.y + b2i);
    if (j == 0) Srow[0] = make_float2(base1, base0 + b2i);

    if (i == 0) {
        ws[OFF_T + j] = tj;
        float* bins = ws + OFF_BIN;
        bins[j] = 0.f; bins[j + 128] = 0.f; bins[j + 256] = 0.f; bins[j + 384] = 0.f;
        if (j < 2) ws[OFF_ST + 2*(1 - par) + j] = 0.f;
    }
}

// 256 blocks x 1024: per-sample bin + per-interval (cnt, sum x, sum x^2)
__global__ __launch_bounds__(1024) void k_hist(float* __restrict__ ws, int rev) {
    const int tid = threadIdx.x;
    const int b = blockIdx.x * 1024 + tid;
    __shared__ float lt[H_];
    __shared__ float lb[4 * 396];
    if (tid < H_) lt[tid] = ws[OFF_T + tid];
    for (int e = tid; e < 4 * 396; e += 1024) lb[e] = 0.f;
    __syncthreads();
    float x = rev ? ws[BN_ + b] : ws[b];
    int bin = 0;
    #pragma unroll 16
    for (int q = 0; q < H_; q++) bin += (lt[q] < x) ? 1 : 0;
    ((unsigned char*)(ws + OFF_BB))[b] = (unsigned char)bin;
    float* lbr = lb + ((tid >> 6) & 3) * 396;
    atomicAdd(&lbr[bin], 1.f);
    atomicAdd(&lbr[132 + bin], x);
    atomicAdd(&lbr[264 + bin], x * x);
    __syncthreads();
    float* bins = ws + OFF_BIN;
    for (int e = tid; e < 396; e += 1024) {
        float v = lb[e] + lb[396 + e] + lb[792 + e] + lb[1188 + e];
        atomicAdd(&bins[e], v);
    }
}

// 256 blocks x 1024: exact BN2 stats from interval moments (redundant per
// block), then per-sample apply: h2=relu(x*S1f+S0f), st=wf@h2+bf, coupling
// update. Last layer fuses sigmoid + log-det output.
__global__ __launch_bounds__(1024, 2) void k_step(
    const float* __restrict__ bn2g, const float* __restrict__ bn2b,
    const float* __restrict__ wf, const float* __restrict__ bf,
    float* __restrict__ ws, float* __restrict__ out,
    int l, int rev, int last, int par) {
    __shared__ float2 tile[32 * LSTR];
    __shared__ float LM[H_], LR[H_], LB2[H_];
    __shared__ float rsc[32];
    const int tid = threadIdx.x;
    const float2* Sg = (const float2*)(ws + OFF_S);
    const float* bins = ws + OFF_BIN;

    { // prologue: mean_i, var_i  (exact from interval moments)
        int i = tid & 127, cch = tid >> 7;
        int k0 = cch * 17, k1 = (k0 + 17 < NBINS) ? k0 + 17 : NBINS;
        float pm = 0.f, pe = 0.f;
        for (int k = k0; k < k1; k++) {
            float2 s = Sg[i * SSTR + k];
            float cn = bins[k], sx = bins[132 + k], sxx = bins[264 + k];
            pm += s.x * sx + s.y * cn;
            pe += s.x * s.x * sxx + 2.f * s.x * s.y * sx + s.y * s.y * cn;
        }
        float* sc1 = (float*)tile;
        float* sc2 = sc1 + 1024;
        sc1[tid] = pm; sc2[tid] = pe;
        __syncthreads();
        if (tid < H_) {
            float m = 0.f, e2 = 0.f;
            for (int cc = 0; cc < 8; cc++) { m += sc1[cc*128 + tid]; e2 += sc2[cc*128 + tid]; }
            float mean = m * (1.f / BN_);
            float var = fmaxf(e2 * (1.f / BN_) - mean * mean, 0.f);
            LM[tid] = mean;
            LR[tid] = bn2g[l*H_ + tid] * rsqrtf(var + 1e-5f);
            LB2[tid] = bn2b[l*H_ + tid];
        }
        __syncthreads();
    }

    const int b = blockIdx.x * 1024 + tid;
    float x0v = ws[b], x1v = ws[BN_ + b];
    float xin = rev ? x1v : x0v;
    float xo  = rev ? x0v : x1v;
    int kb = ((const unsigned char*)(ws + OFF_BB))[b];
    float stx = bf[2*l], sty = bf[2*l + 1];

    for (int ci = 0; ci < 4; ci++) {
        __syncthreads();
        const int i0 = ci * 32;
        for (int e = tid; e < 32 * SSTR; e += 1024) {
            int il = e / SSTR, k = e - il * SSTR;
            if (k < NBINS) {
                int ia = i0 + il;
                float2 s = Sg[ia * SSTR + k];
                float R = LR[ia];
                tile[il * LSTR + k] = make_float2(s.x * R, (s.y - LM[ia]) * R + LB2[ia]);
            }
        }
        __syncthreads();
        #pragma unroll
        for (int il = 0; il < 32; il++) {
            float2 s = tile[il * LSTR + kb];
            float h = fmaxf(fmaf(xin, s.x, s.y), 0.f);
            stx = fmaf(wf[l*2*H_ + i0 + il], h, stx);
            sty = fmaf(wf[l*2*H_ + H_ + i0 + il], h, sty);
        }
    }

    float s = tanhf(stx);
    float y = expf(s) * xo + sty;
    float sl = ws[2*BN_ + b] + s;

    if (!last) {
        if (rev) ws[b] = y; else ws[BN_ + b] = y;
        ws[2*BN_ + b] = sl;
        // next layer's xin stats = stats of y
        float s1 = y, s2 = y * y;
        for (int off = 32; off; off >>= 1) {
            s1 += __shfl_down(s1, off);
            s2 += __shfl_down(s2, off);
        }
        int lane = tid & 63, wid = tid >> 6;
        if (lane == 0) { rsc[wid] = s1; rsc[16 + wid] = s2; }
        __syncthreads();
        if (tid == 0) {
            float a = 0.f, c = 0.f;
            for (int w = 0; w < 16; w++) { a += rsc[w]; c += rsc[16 + w]; }
            atomicAdd(&ws[OFF_ST + 2*(1 - par)], a);
            atomicAdd(&ws[OFF_ST + 2*(1 - par) + 1], c);
        }
    } else {
        // l=7: rev=0, x0 unchanged, y is new x1
        float z0 = 1.f / (1.f + expf(-x0v));
        float z1 = 1.f / (1.f + expf(-y));
        ((float2*)out)[b] = make_float2(z0, z1);
        out[2*BN_ + b] = sl + logf(z0 * (1.f - z0) + 1e-4f)
                            + logf(z1 * (1.f - z1) + 1e-4f);
    }
}

extern "C" void kernel_launch(void* const* d_in, const int* in_sizes, int n_in,
                              void* d_out, int out_size, void* d_ws, size_t ws_size,
                              hipStream_t stream) {
    const float* x    = (const float*)d_in[0];
    const float* v1   = (const float*)d_in[1];
    const float* g1   = (const float*)d_in[2];
    // d_in[3] = b1: cancels exactly inside BN1 (affine input), unused.
    const float* bn1g = (const float*)d_in[4];
    const float* bn1b = (const float*)d_in[5];
    const float* v2   = (const float*)d_in[6];
    const float* g2   = (const float*)d_in[7];
    const float* b2   = (const float*)d_in[8];
    const float* bn2g = (const float*)d_in[9];
    const float* bn2b = (const float*)d_in[10];
    const float* wf   = (const float*)d_in[11];
    const float* bf   = (const float*)d_in[12];
    float* ws  = (float*)d_ws;
    float* out = (float*)d_out;

    k_zero<<<1, 64, 0, stream>>>(ws);
    k_init<<<BN_/1024, 1024, 0, stream>>>(x, ws);
    for (int l = 0; l < 8; l++) {
        int rev = (l % 2 == 0) ? 1 : 0;
        int par = l & 1;
        int last = (l == 7) ? 1 : 0;
        k_prep<<<128, 128, 0, stream>>>(v1, g1, bn1g, bn1b, v2, g2, b2, ws, l, par);
        k_hist<<<BN_/1024, 1024, 0, stream>>>(ws, rev);
        k_step<<<BN_/1024, 1024, 0, stream>>>(bn2g, bn2b, wf, bf, ws, out, l, rev, last, par);
    }
}